// Round 1
// baseline (6606.354 us; speedup 1.0000x reference)
//
#include <hip/hip_runtime.h>
#include <cstdint>
#include <cstddef>

#define D_MODEL   1536
#define N_HEADS   48
#define HEAD_DIM  64
#define D_STATE   128
#define N_LAYER   4
#define K_CONV    4
#define D_INNER   3072      // N_HEADS*HEAD_DIM
#define CONV_DIM  3328      // D_INNER + 2*D_STATE
#define D_IN_PROJ 6448      // 2*D_INNER + 2*D_STATE + N_HEADS
#define BATCH     4
#define SEQ       512
#define NROWS     (BATCH*SEQ)   // 2048
#define EPS       1e-5f
#define FEAT_DIM  1552      // D_MODEL + 16

// ---------------- utility: block reduction (256 threads = 4 waves) ----------
__device__ __forceinline__ float block_reduce_sum(float v, float* red) {
    #pragma unroll
    for (int off = 32; off >= 1; off >>= 1) v += __shfl_xor(v, off);
    int wid = threadIdx.x >> 6;
    if ((threadIdx.x & 63) == 0) red[wid] = v;
    __syncthreads();
    if (threadIdx.x == 0) {
        float s = 0.f;
        int nw = blockDim.x >> 6;
        for (int i = 0; i < nw; ++i) s += red[i];
        red[0] = s;
    }
    __syncthreads();
    return red[0];
}

// ---------------- embedding gather ----------------
__global__ __launch_bounds__(256) void k_embed(const int* __restrict__ ids,
                                               const float* __restrict__ emb,
                                               float* __restrict__ h) {
    int row = blockIdx.x;                       // b*SEQ + l
    int id  = ids[row];
    const float4* src = (const float4*)(emb + (size_t)id * D_MODEL);
    float4*       dst = (float4*)(h + (size_t)row * D_MODEL);
    for (int i = threadIdx.x; i < D_MODEL / 4; i += 256) dst[i] = src[i];
}

// ---------------- rmsnorm over D_MODEL=1536 ----------------
__global__ __launch_bounds__(256) void k_rmsnorm(const float* __restrict__ x,
                                                 const float* __restrict__ w,
                                                 float* __restrict__ o) {
    __shared__ float red[4];
    size_t row = blockIdx.x;
    const float* xr = x + row * D_MODEL;
    float v[6];
    float ss = 0.f;
    #pragma unroll
    for (int i = 0; i < 6; ++i) {
        int c = threadIdx.x + i * 256;
        v[i] = xr[c];
        ss += v[i] * v[i];
    }
    float tot = block_reduce_sum(ss, red);
    float rs = rsqrtf(tot / (float)D_MODEL + EPS);
    float* orow = o + row * D_MODEL;
    #pragma unroll
    for (int i = 0; i < 6; ++i) {
        int c = threadIdx.x + i * 256;
        orow[c] = v[i] * rs * w[c];
    }
}

// ---------------- fp32 GEMM:  C[m][n] (+)= sum_k A[m][k]*Bw[n][k] ----------
// A: M x K row-major (M = 2048, multiple of 128). Bw: N x K row-major.
// 128x128 tile, BK=16, 256 threads, 8x8 per-thread micro-tile.
template<int BETA>
__global__ __launch_bounds__(256) void gemm_nt(const float* __restrict__ A,
                                               const float* __restrict__ Bw,
                                               float* __restrict__ C,
                                               int N, int K) {
    __shared__ __align__(16) float As[16][132];
    __shared__ __align__(16) float Bs[16][132];
    int t  = threadIdx.x;
    int bm = blockIdx.y * 128;
    int bn = blockIdx.x * 128;
    int tx = t & 15, ty = t >> 4;

    float acc[8][8];
    #pragma unroll
    for (int i = 0; i < 8; ++i)
        #pragma unroll
        for (int j = 0; j < 8; ++j) acc[i][j] = 0.f;

    int nkt = K >> 4;
    for (int kt = 0; kt < nkt; ++kt) {
        int k0 = kt << 4;
        #pragma unroll
        for (int u = 0; u < 2; ++u) {
            int i   = t + u * 256;          // 0..511
            int row = i >> 2;               // 0..127
            int kq  = (i & 3) << 2;         // 0,4,8,12
            float4 av = *(const float4*)&A[(size_t)(bm + row) * K + k0 + kq];
            As[kq + 0][row] = av.x; As[kq + 1][row] = av.y;
            As[kq + 2][row] = av.z; As[kq + 3][row] = av.w;
            int nrow = bn + row;
            float4 bv = make_float4(0.f, 0.f, 0.f, 0.f);
            if (nrow < N) bv = *(const float4*)&Bw[(size_t)nrow * K + k0 + kq];
            Bs[kq + 0][row] = bv.x; Bs[kq + 1][row] = bv.y;
            Bs[kq + 2][row] = bv.z; Bs[kq + 3][row] = bv.w;
        }
        __syncthreads();
        #pragma unroll
        for (int kk = 0; kk < 16; ++kk) {
            float4 a0 = *(const float4*)&As[kk][ty * 8];
            float4 a1 = *(const float4*)&As[kk][ty * 8 + 4];
            float4 b0 = *(const float4*)&Bs[kk][tx * 8];
            float4 b1 = *(const float4*)&Bs[kk][tx * 8 + 4];
            float a[8] = {a0.x, a0.y, a0.z, a0.w, a1.x, a1.y, a1.z, a1.w};
            float bb[8] = {b0.x, b0.y, b0.z, b0.w, b1.x, b1.y, b1.z, b1.w};
            #pragma unroll
            for (int i = 0; i < 8; ++i)
                #pragma unroll
                for (int j = 0; j < 8; ++j) acc[i][j] += a[i] * bb[j];
        }
        __syncthreads();
    }
    // store (N % 4 == 0 so each float4 is fully in/out of range)
    #pragma unroll
    for (int i = 0; i < 8; ++i) {
        int m = bm + ty * 8 + i;
        float* crow = C + (size_t)m * N;
        #pragma unroll
        for (int jq = 0; jq < 2; ++jq) {
            int n = bn + tx * 8 + jq * 4;
            if (n < N) {
                float4 val = make_float4(acc[i][jq * 4 + 0], acc[i][jq * 4 + 1],
                                         acc[i][jq * 4 + 2], acc[i][jq * 4 + 3]);
                if (BETA) {
                    float4 old = *(const float4*)&crow[n];
                    val.x += old.x; val.y += old.y; val.z += old.z; val.w += old.w;
                }
                *(float4*)&crow[n] = val;
            }
        }
    }
}

// ---------------- depthwise causal conv (K=4) + bias + silu, plus dt softplus
__global__ __launch_bounds__(256) void k_conv_dt(const float* __restrict__ zx,
                                                 const float* __restrict__ cw,
                                                 const float* __restrict__ cb,
                                                 const float* __restrict__ dtbias,
                                                 float* __restrict__ xbc,
                                                 float* __restrict__ dtb) {
    int row = blockIdx.x;               // b*SEQ + l
    int l   = row & (SEQ - 1);
    const float* base = zx + D_INNER;   // xBC slice of zxbcdt
    #pragma unroll 1
    for (int it = 0; it < 13; ++it) {
        int c = threadIdx.x + it * 256;     // 0..3327
        float4 w4 = *(const float4*)&cw[c * 4];
        float wv[4] = {w4.x, w4.y, w4.z, w4.w};
        float acc = cb[c];
        #pragma unroll
        for (int k = 0; k < 4; ++k) {
            int ll = l - 3 + k;
            if (ll >= 0)
                acc += wv[k] * base[(size_t)(row - 3 + k) * D_IN_PROJ + c];
        }
        // silu
        acc = acc / (1.f + expf(-acc));
        xbc[(size_t)row * CONV_DIM + c] = acc;
    }
    if (threadIdx.x < N_HEADS) {
        int hh = threadIdx.x;
        float x = zx[(size_t)row * D_IN_PROJ + D_INNER + CONV_DIM + hh] + dtbias[hh];
        float sp = (x > 20.f) ? x : log1pf(expf(x));
        dtb[(size_t)row * N_HEADS + hh] = sp;
    }
}

// ---------------- SSD scan ----------------
// grid: BATCH * N_HEADS * 2 blocks (half = 32 of the 64 p's), 256 threads.
// thread t: pg = t>>3 (p within half), g = t&7 (16-state chunk of n).
__global__ __launch_bounds__(256) void k_scan(const float* __restrict__ xbc,
                                              const float* __restrict__ dtb,
                                              const float* __restrict__ A_log,
                                              const float* __restrict__ Dvec,
                                              float* __restrict__ y) {
    __shared__ __align__(16) float sB[D_STATE];
    __shared__ __align__(16) float sC[D_STATE];
    __shared__ __align__(16) float sX[32];
    __shared__ float sDt[SEQ];
    __shared__ float sDec[SEQ];

    int bid  = blockIdx.x;
    int b    = bid / (N_HEADS * 2);
    int rem  = bid % (N_HEADS * 2);
    int head = rem >> 1, half = rem & 1;
    int t    = threadIdx.x;
    int pg   = t >> 3, g = t & 7;

    float A  = -expf(A_log[head]);
    float Dv = Dvec[head];

    for (int i = t; i < SEQ; i += 256) {
        float dtv = dtb[(size_t)(b * SEQ + i) * N_HEADS + head];
        sDt[i]  = dtv;
        sDec[i] = expf(dtv * A);
    }

    float st[16];
    #pragma unroll
    for (int j = 0; j < 16; ++j) st[j] = 0.f;
    __syncthreads();

    int xoff = head * HEAD_DIM + half * 32;
    for (int l = 0; l < SEQ; ++l) {
        size_t row = (size_t)(b * SEQ + l);
        const float* xr = xbc + row * CONV_DIM;
        if (t < 128) sB[t] = xr[D_INNER + t];
        else         sC[t - 128] = xr[D_INNER + D_STATE + (t - 128)];
        if (t < 32)  sX[t] = xr[xoff + t];
        __syncthreads();

        float dtv = sDt[l], dec = sDec[l];
        float xv  = sX[pg];
        float dtx = dtv * xv;
        float ysum = 0.f;
        const float4* b4 = (const float4*)(sB + g * 16);
        const float4* c4 = (const float4*)(sC + g * 16);
        #pragma unroll
        for (int q = 0; q < 4; ++q) {
            float4 bb = b4[q], cc = c4[q];
            st[q*4+0] = st[q*4+0] * dec + dtx * bb.x; ysum += st[q*4+0] * cc.x;
            st[q*4+1] = st[q*4+1] * dec + dtx * bb.y; ysum += st[q*4+1] * cc.y;
            st[q*4+2] = st[q*4+2] * dec + dtx * bb.z; ysum += st[q*4+2] * cc.z;
            st[q*4+3] = st[q*4+3] * dec + dtx * bb.w; ysum += st[q*4+3] * cc.w;
        }
        ysum += __shfl_xor(ysum, 1);
        ysum += __shfl_xor(ysum, 2);
        ysum += __shfl_xor(ysum, 4);
        if (g == 0) y[row * D_INNER + xoff + pg] = ysum + Dv * xv;
        __syncthreads();
    }
}

// ---------------- gated rmsnorm over D_INNER=3072 (in-place on y) ----------
__global__ __launch_bounds__(256) void k_gated_norm(float* __restrict__ y,
                                                    const float* __restrict__ zx,
                                                    const float* __restrict__ gw) {
    __shared__ float red[4];
    size_t row = blockIdx.x;
    float* yr = y + row * D_INNER;
    const float* zr = zx + row * D_IN_PROJ;   // z = first D_INNER of zxbcdt
    float v[12];
    float ss = 0.f;
    #pragma unroll
    for (int i = 0; i < 12; ++i) {
        int c = threadIdx.x + i * 256;
        float z  = zr[c];
        float val = yr[c] * (z / (1.f + expf(-z)));
        v[i] = val;
        ss += val * val;
    }
    float tot = block_reduce_sum(ss, red);
    float rs = rsqrtf(tot / (float)D_INNER + EPS);
    #pragma unroll
    for (int i = 0; i < 12; ++i) {
        int c = threadIdx.x + i * 256;
        yr[c] = v[i] * rs * gw[c];
    }
}

// ---------------- masked mean pooling ----------------
__global__ __launch_bounds__(256) void k_masked_mean(const float* __restrict__ xn,
                                                     const int* __restrict__ mask,
                                                     float* __restrict__ text) {
    int b = blockIdx.y;
    int d = blockIdx.x * 256 + threadIdx.x;
    float acc = 0.f, msum = 0.f;
    for (int l = 0; l < SEQ; ++l) {
        float m = (float)mask[b * SEQ + l];
        acc  += m * xn[(size_t)(b * SEQ + l) * D_MODEL + d];
        msum += m;
    }
    text[b * D_MODEL + d] = acc / fmaxf(msum, 1e-9f);
}

// ---------------- heads: out[b][j] = feat . W[j] + bias[j] ----------------
__global__ __launch_bounds__(256) void k_heads(const float* __restrict__ text,
                                               const int* __restrict__ cats,
                                               const float* __restrict__ cat_emb,
                                               const float* __restrict__ qw,
                                               const float* __restrict__ qb,
                                               const float* __restrict__ aw,
                                               const float* __restrict__ ab,
                                               float* __restrict__ out) {
    __shared__ float red[4];
    int b = blockIdx.x / 30;
    int j = blockIdx.x % 30;
    const float* w = (j < 21) ? qw + (size_t)j * FEAT_DIM
                              : aw + (size_t)(j - 21) * FEAT_DIM;
    float bias = (j < 21) ? qb[j] : ab[j - 21];
    float s = 0.f;
    for (int d = threadIdx.x; d < FEAT_DIM; d += 256) {
        float f = (d < D_MODEL) ? text[b * D_MODEL + d]
                                : cat_emb[cats[b] * 16 + (d - D_MODEL)];
        s += f * w[d];
    }
    float tot = block_reduce_sum(s, red);
    if (threadIdx.x == 0) out[b * 30 + j] = tot + bias;
}

// ---------------- launch ----------------
extern "C" void kernel_launch(void* const* d_in, const int* in_sizes, int n_in,
                              void* d_out, int out_size, void* d_ws, size_t ws_size,
                              hipStream_t stream) {
    const int*   ids         = (const int*)d_in[0];
    const int*   mask        = (const int*)d_in[1];
    const int*   cats        = (const int*)d_in[2];
    const float* embedding   = (const float*)d_in[3];
    const float* norm_w      = (const float*)d_in[4];
    const float* in_proj     = (const float*)d_in[5];
    const float* conv_w      = (const float*)d_in[6];
    const float* conv_b      = (const float*)d_in[7];
    const float* dt_bias     = (const float*)d_in[8];
    const float* A_log       = (const float*)d_in[9];
    const float* Dvec        = (const float*)d_in[10];
    const float* gnorm_w     = (const float*)d_in[11];
    const float* out_proj    = (const float*)d_in[12];
    const float* final_nw    = (const float*)d_in[13];
    const float* cat_emb     = (const float*)d_in[14];
    const float* head_q_w    = (const float*)d_in[15];
    const float* head_q_b    = (const float*)d_in[16];
    const float* head_a_w    = (const float*)d_in[17];
    const float* head_a_b    = (const float*)d_in[18];

    float* ws   = (float*)d_ws;
    float* h    = ws;                                      // 2048*1536
    float* zx   = h   + (size_t)NROWS * D_MODEL;           // 2048*6448
    float* xn   = zx  + (size_t)NROWS * D_IN_PROJ;         // region2 (max 2048*3328)
    float* xbc  = xn;                                      // alias: xn dead after GEMM
    float* dtb  = xn  + (size_t)NROWS * CONV_DIM;          // 2048*48
    float* y    = dtb + (size_t)NROWS * N_HEADS;           // 2048*3072
    float* text = y   + (size_t)NROWS * D_INNER;           // 4*1536

    k_embed<<<NROWS, 256, 0, stream>>>(ids, embedding, h);

    for (int layer = 0; layer < N_LAYER; ++layer) {
        k_rmsnorm<<<NROWS, 256, 0, stream>>>(h, norm_w + layer * D_MODEL, xn);

        dim3 g1((D_IN_PROJ + 127) / 128, NROWS / 128);
        gemm_nt<0><<<g1, 256, 0, stream>>>(
            xn, in_proj + (size_t)layer * D_IN_PROJ * D_MODEL, zx, D_IN_PROJ, D_MODEL);

        k_conv_dt<<<NROWS, 256, 0, stream>>>(
            zx, conv_w + (size_t)layer * CONV_DIM * K_CONV,
            conv_b + (size_t)layer * CONV_DIM,
            dt_bias + (size_t)layer * N_HEADS, xbc, dtb);

        k_scan<<<BATCH * N_HEADS * 2, 256, 0, stream>>>(
            xbc, dtb, A_log + (size_t)layer * N_HEADS,
            Dvec + (size_t)layer * N_HEADS, y);

        k_gated_norm<<<NROWS, 256, 0, stream>>>(y, zx, gnorm_w + (size_t)layer * D_INNER);

        dim3 g2(D_MODEL / 128, NROWS / 128);
        gemm_nt<1><<<g2, 256, 0, stream>>>(
            y, out_proj + (size_t)layer * D_MODEL * D_INNER, h, D_MODEL, D_INNER);
    }

    k_rmsnorm<<<NROWS, 256, 0, stream>>>(h, final_nw, xn);
    dim3 g3(D_MODEL / 256, BATCH);
    k_masked_mean<<<g3, 256, 0, stream>>>(xn, mask, text);
    k_heads<<<BATCH * 30, 256, 0, stream>>>(
        text, cats, cat_emb, head_q_w, head_q_b, head_a_w, head_a_b, (float*)d_out);
}